// Round 4
// baseline (344.587 us; speedup 1.0000x reference)
//
#include <hip/hip_runtime.h>

// SmartDerivatives R12: R8's dense staging + R11's atomic-free per-wave
// consumption, 5 row-aligned chunks -> 38.3KB LDS -> 4 blocks/CU.
//
// Ladder: R8 (stage, no atomics, 40%-thread consume, ws+combine) ~60us;
// R9 (stream, divergent) 114; R10 (stage, LDS atomics) 148, VALUBusy 3% =
// atomic-unit serialization; R11 (stream, atomic-free, 24B-stride loads) ~66.
// Lessons: LDS atomics are poison; strided per-lane global loads are poison;
// R8's flaw was 2 blocks/CU + thread-starved consume + ws round-trip.
//
// R12: per chunk {dense float4 stage of z=left*x -> barrier -> all-wave
// consume -> barrier}. Wave owns rows (round-robin in chunk), lane owns desc.
// Row channels 0..2: regs + one shuffle reduce (single writer -> racc[a]).
// Col channels 3..5: non-atomic b128 RMW into per-wave cacc[w][j] — within a
// row, lanes hit distinct consecutive j: conflict-free, race-free (in-order
// per-wave DS pipe). z reads are b64 at word-stride 6 -> 2 lanes/bank = free.
// 4 blocks/CU x 8 waves = 32 waves/CU; grid 1024 = one residency round;
// stage(B) overlaps consume(A) across resident blocks. Epilogue fuses the
// old combine kernel: out = (racc + sum_w cacc)^2.

#define D_DESC  4950
#define BATCH   1024
#define NOUT    300
#define NW      8        // waves per block (512 threads)
#define NCH     5
#define TILE_F4 1551     // max chunk float4 count (chunk0), 24816 B

__device__ __forceinline__ int rowstart(int i) { return (i * (199 - i)) >> 1; }

__global__ __launch_bounds__(512, 8)
void sd_kernel(const float* __restrict__ x,
               const float* __restrict__ left,
               float* __restrict__ out)
{
    __shared__ float4 sz4[TILE_F4];     // z tile for current chunk
    __shared__ float4 cacc[NW * 100];   // [wave][atom] col channels 3..5
    __shared__ float4 racc[100];        // [atom] row channels 0..2

    const int b    = blockIdx.x;
    const int tid  = threadIdx.x;
    const int lane = tid & 63;
    const int w    = tid >> 6;

    // Row-aligned chunks: rows [CR0[c],CR0[c+1]), descs [CS[c],CS[c+1]).
    // f4 ranges chosen to cover floats [CS*6, CE*6) (boundary f4 overlap ok).
    constexpr int CR0[NCH + 1] = {0, 11, 23, 37, 55, 99};
    constexpr int F4S[NCH]     = {0, 1551, 3036, 4495, 5940};
    constexpr int F4E[NCH]     = {1551, 3036, 4496, 5940, 7425};

    for (int t = lane; t < 100; t += 64)
        cacc[w * 100 + t] = float4{0.f, 0.f, 0.f, 0.f};
    if (tid < 100) racc[tid] = float4{0.f, 0.f, 0.f, 0.f};  // atom 99 stays 0

    const float* __restrict__ xb = x + (size_t)b * D_DESC;
    const float* __restrict__ Lf = left + (size_t)b * (D_DESC * 6);
    const float* sz = (const float*)sz4;

    #pragma unroll
    for (int c = 0; c < NCH; ++c) {
        const int f4s = F4S[c];
        const int f4c = F4E[c] - f4s;
        const int zb  = f4s * 4;                  // float offset of tile[0]
        const float4* __restrict__ lb4 = (const float4*)Lf + f4s;

        // ---- stage z = left * x (dense, coalesced; x from L1/L2).
        // float4 idx covers frame floats g..g+3; r = g%6 in {0,2,4}; only
        // r==4 straddles two descriptors (elements 2,3 -> d0+1).
        #pragma unroll
        for (int k = 0; k < 4; ++k) {
            const int idx = tid + k * 512;
            if (idx < f4c) {
                const float4 L = lb4[idx];
                const int g  = (f4s + idx) * 4;
                const int d0 = g / 6;
                const int r  = g - 6 * d0;
                const float x0 = xb[d0];
                const float x1 = xb[(g + 3) / 6];   // == x0 unless r==4
                float4 z;
                z.x = L.x * x0;
                z.y = L.y * x0;
                z.z = L.z * ((r + 2 >= 6) ? x1 : x0);
                z.w = L.w * ((r + 3 >= 6) ? x1 : x0);
                sz4[idx] = z;
            }
        }
        __syncthreads();                           // tile ready

        // ---- consume: wave w owns rows CR0[c]+w, +NW, ... of this chunk
        for (int a = CR0[c] + w; a < CR0[c + 1]; a += NW) {
            const int rs  = rowstart(a);
            const int len = 99 - a;
            const float* __restrict__ base = sz + (rs * 6 - zb);
            float s0 = 0.f, s1 = 0.f, s2 = 0.f;

            for (int d0 = 0; d0 < len; d0 += 64) {
                const int d = d0 + lane;
                if (d < len) {
                    const float2 c01 = *(const float2*)(base + d * 6);
                    const float2 c23 = *(const float2*)(base + d * 6 + 2);
                    const float2 c45 = *(const float2*)(base + d * 6 + 4);
                    s0 += c01.x; s1 += c01.y; s2 += c23.x;
                    // per-wave private, j distinct & consecutive across lanes
                    float4* slot = &cacc[w * 100 + (a + 1 + d)];
                    float4 cur = *slot;            // ds_read_b128
                    cur.x += c23.y;
                    cur.y += c45.x;
                    cur.z += c45.y;
                    *slot = cur;                   // ds_write_b128
                }
            }

            const int nact = len < 64 ? len : 64;
            #pragma unroll
            for (int off = 32; off >= 1; off >>= 1) {
                if (nact > off) {
                    s0 += __shfl_down(s0, off);
                    s1 += __shfl_down(s1, off);
                    s2 += __shfl_down(s2, off);
                }
            }
            if (lane == 0) racc[a] = float4{s0, s1, s2, 0.f};
        }
        __syncthreads();                           // tile consumed
    }

    // ---- epilogue: out[b, t*3+dim] = (racc[t] + sum_w cacc[w][t])^2
    if (tid < 100) {
        float4 v = racc[tid];
        #pragma unroll
        for (int ww = 0; ww < NW; ++ww) {
            const float4 cc = cacc[ww * 100 + tid];
            v.x += cc.x; v.y += cc.y; v.z += cc.z;
        }
        float* __restrict__ o = out + (size_t)b * NOUT + tid * 3;
        o[0] = v.x * v.x;
        o[1] = v.y * v.y;
        o[2] = v.z * v.z;
    }
}

extern "C" void kernel_launch(void* const* d_in, const int* in_sizes, int n_in,
                              void* d_out, int out_size, void* d_ws, size_t ws_size,
                              hipStream_t stream) {
    (void)in_sizes; (void)n_in; (void)d_ws; (void)ws_size; (void)out_size;
    const float* x    = (const float*)d_in[0];   // [BATCH, D]
    const float* left = (const float*)d_in[1];   // [BATCH*D*6]
    sd_kernel<<<BATCH, 512, 0, stream>>>(x, left, (float*)d_out);
}

// Round 5
// 335.022 us; speedup vs baseline: 1.0286x; 1.0286x over previous
//
#include <hip/hip_runtime.h>

// SmartDerivatives R13: R12 skeleton, DS-pipe diet.
//
// Ladder: R8 (staged, NO shuffles) ~55us; R11 (stream, shuffles+b128 RMW)
// ~63; R12 (staged, shuffles+b128 RMW) ~69. Different memory strategies,
// same floor -> shared bottleneck is the consume DS load:
//  (a) __shfl_down reduce = ds_bpermute: ~1780 DS instr/block;
//  (b) cacc float4 RMW: 16B stride -> bank (4j)%32 -> 8-way conflict (2.94x)
//      on every b128 read AND write.
// R13 changes ONLY these two:
//  1. DPP wave reduction (row_shr 1/2/4/8 + row_bcast 15/31, result lane 63)
//     -> reduction moves to the idle VALU pipe, zero DS.
//  2. SoA cacc: float cacc[3][NW*104], b32 RMW at 4B stride = 2 lanes/bank
//     = conflict-free (m136). Still per-wave-private, atomic-free.
// Stage, row-aligned 5-chunk tiling, barriers, epilogue: unchanged from R12.

#define D_DESC  4950
#define BATCH   1024
#define NOUT    300
#define NW      8        // waves per block (512 threads)
#define NCH     5
#define TILE_F4 1551     // max chunk float4 count (chunk0), 24816 B
#define CACC_W  104      // padded per-wave stride (j in [1,99])

__device__ __forceinline__ int rowstart(int i) { return (i * (199 - i)) >> 1; }

// v += dpp_moved(v); CTRL/RM are immediates via template (builtin needs ICE).
template <int CTRL, int RM>
__device__ __forceinline__ float dpp_add(float v) {
    const int t = __builtin_amdgcn_update_dpp(
        0, __float_as_int(v), CTRL, RM, 0xf, true);  // bound_ctrl: OOB -> 0
    return v + __int_as_float(t);
}

// Full wave64 sum; valid in lane 63. Classic gfx9 sequence (rocPRIM).
__device__ __forceinline__ float wave_sum(float v) {
    v = dpp_add<0x111, 0xf>(v);   // row_shr:1
    v = dpp_add<0x112, 0xf>(v);   // row_shr:2
    v = dpp_add<0x114, 0xf>(v);   // row_shr:4
    v = dpp_add<0x118, 0xf>(v);   // row_shr:8
    v = dpp_add<0x142, 0xa>(v);   // row_bcast:15 -> rows 1,3
    v = dpp_add<0x143, 0xc>(v);   // row_bcast:31 -> rows 2,3
    return v;
}

__global__ __launch_bounds__(512, 8)
void sd_kernel(const float* __restrict__ x,
               const float* __restrict__ left,
               float* __restrict__ out)
{
    __shared__ float4 sz4[TILE_F4];        // z tile for current chunk
    __shared__ float  cacc[3][NW * CACC_W];// [ch-3][wave*stride + j], SoA
    __shared__ float4 racc[100];           // [atom] row channels 0..2

    const int b    = blockIdx.x;
    const int tid  = threadIdx.x;
    const int lane = tid & 63;
    const int w    = tid >> 6;

    // Row-aligned chunks: rows [CR0[c],CR0[c+1]); f4 ranges cover their floats.
    constexpr int CR0[NCH + 1] = {0, 11, 23, 37, 55, 99};
    constexpr int F4S[NCH]     = {0, 1551, 3036, 4495, 5940};
    constexpr int F4E[NCH]     = {1551, 3036, 4496, 5940, 7425};

    // zero own wave's cacc slice (same-wave DS ordering covers own use;
    // cross-wave visibility guaranteed by the first chunk barrier)
    for (int t = lane; t < CACC_W; t += 64) {
        cacc[0][w * CACC_W + t] = 0.0f;
        cacc[1][w * CACC_W + t] = 0.0f;
        cacc[2][w * CACC_W + t] = 0.0f;
    }
    if (tid == 0) racc[99] = float4{0.f, 0.f, 0.f, 0.f};  // atom 99: no row part

    const float* __restrict__ xb = x + (size_t)b * D_DESC;
    const float* __restrict__ Lf = left + (size_t)b * (D_DESC * 6);
    const float* sz = (const float*)sz4;

    #pragma unroll
    for (int c = 0; c < NCH; ++c) {
        const int f4s = F4S[c];
        const int f4c = F4E[c] - f4s;
        const int zb  = f4s * 4;                  // float offset of tile[0]
        const float4* __restrict__ lb4 = (const float4*)Lf + f4s;

        // ---- stage z = left * x (dense, coalesced; x from L1/L2). Unchanged.
        #pragma unroll
        for (int k = 0; k < 4; ++k) {
            const int idx = tid + k * 512;
            if (idx < f4c) {
                const float4 L = lb4[idx];
                const int g  = (f4s + idx) * 4;
                const int d0 = g / 6;
                const int r  = g - 6 * d0;
                const float x0 = xb[d0];
                const float x1 = xb[(g + 3) / 6];   // == x0 unless r==4
                float4 z;
                z.x = L.x * x0;
                z.y = L.y * x0;
                z.z = L.z * ((r + 2 >= 6) ? x1 : x0);
                z.w = L.w * ((r + 3 >= 6) ? x1 : x0);
                sz4[idx] = z;
            }
        }
        __syncthreads();                           // tile ready

        // ---- consume: wave w owns rows CR0[c]+w, +NW, ...
        for (int a = CR0[c] + w; a < CR0[c + 1]; a += NW) {
            const int rs  = rowstart(a);
            const int len = 99 - a;
            const float* __restrict__ base = sz + (rs * 6 - zb);
            float s0 = 0.f, s1 = 0.f, s2 = 0.f;

            // len <= 99 -> at most 2 lane-parallel iterations
            {
                const int d = lane;
                if (d < len) {
                    const float2 c01 = *(const float2*)(base + d * 6);
                    const float2 c23 = *(const float2*)(base + d * 6 + 2);
                    const float2 c45 = *(const float2*)(base + d * 6 + 4);
                    s0 += c01.x; s1 += c01.y; s2 += c23.x;
                    const int j = a + 1 + d;       // distinct per lane
                    cacc[0][w * CACC_W + j] += c23.y;   // b32 RMW, stride 4B
                    cacc[1][w * CACC_W + j] += c45.x;
                    cacc[2][w * CACC_W + j] += c45.y;
                }
            }
            if (len > 64) {                        // wave-uniform branch
                const int d = lane + 64;
                if (d < len) {
                    const float2 c01 = *(const float2*)(base + d * 6);
                    const float2 c23 = *(const float2*)(base + d * 6 + 2);
                    const float2 c45 = *(const float2*)(base + d * 6 + 4);
                    s0 += c01.x; s1 += c01.y; s2 += c23.x;
                    const int j = a + 1 + d;
                    cacc[0][w * CACC_W + j] += c23.y;
                    cacc[1][w * CACC_W + j] += c45.x;
                    cacc[2][w * CACC_W + j] += c45.y;
                }
            }

            // DPP reduce on the VALU pipe; result in lane 63 (inactive lanes
            // contributed 0). Single writer per row.
            s0 = wave_sum(s0);
            s1 = wave_sum(s1);
            s2 = wave_sum(s2);
            if (lane == 63) racc[a] = float4{s0, s1, s2, 0.f};
        }
        __syncthreads();                           // tile consumed
    }

    // ---- epilogue: out[b, a*3+dim] = (racc[a][dim] + sum_w cacc[dim][w][a])^2
    if (tid < 100) {
        const float4 v = racc[tid];
        float s3 = 0.f, s4 = 0.f, s5 = 0.f;
        #pragma unroll
        for (int ww = 0; ww < NW; ++ww) {
            s3 += cacc[0][ww * CACC_W + tid];
            s4 += cacc[1][ww * CACC_W + tid];
            s5 += cacc[2][ww * CACC_W + tid];
        }
        const float o0 = v.x + s3, o1 = v.y + s4, o2 = v.z + s5;
        float* __restrict__ o = out + (size_t)b * NOUT + tid * 3;
        o[0] = o0 * o0;
        o[1] = o1 * o1;
        o[2] = o2 * o2;
    }
}

extern "C" void kernel_launch(void* const* d_in, const int* in_sizes, int n_in,
                              void* d_out, int out_size, void* d_ws, size_t ws_size,
                              hipStream_t stream) {
    (void)in_sizes; (void)n_in; (void)d_ws; (void)ws_size; (void)out_size;
    const float* x    = (const float*)d_in[0];   // [BATCH, D]
    const float* left = (const float*)d_in[1];   // [BATCH*D*6]
    sd_kernel<<<BATCH, 512, 0, stream>>>(x, left, (float*)d_out);
}